// Round 1
// baseline (28294.495 us; speedup 1.0000x reference)
//
#include <hip/hip_runtime.h>
#include <math.h>

#define TT 512
#define BB 64
#define FF 256
#define HH 1024
#define NBLK 256
#define NCHE 5   // encoder K-chunks: 256 (x) + 4*256 (h)
#define NCHD 8   // decoder K-chunks: 4*256 (enc h) + 4*256 (dec h)

typedef __attribute__((ext_vector_type(8))) short short8;
typedef __attribute__((ext_vector_type(4))) float f32x4;

__device__ __forceinline__ unsigned short f2bf(float f) {
    unsigned u = __float_as_uint(f);
    u += 0x7FFFu + ((u >> 16) & 1u);   // RNE (finite inputs only)
    return (unsigned short)(u >> 16);
}
__device__ __forceinline__ float bf2f(unsigned short u) {
    return __uint_as_float((unsigned)u << 16);
}

// ---------------------------------------------------------------------------
// x[b][t][f] fp32 -> xB[t][b][f] bf16 (batch-major per step). xB lives in
// d_out (dead until out_proj).
// ---------------------------------------------------------------------------
__global__ __launch_bounds__(256) void k_cast_x(const float* __restrict__ x,
                                                unsigned short* __restrict__ xB) {
    int t = blockIdx.x;
    #pragma unroll
    for (int i = 0; i < 16; ++i) {
        int id = threadIdx.x + i * 256;
        int b  = id >> 6;
        int f4 = (id & 63) << 2;
        float4 v = *(const float4*)(x + ((size_t)b * TT + t) * FF + f4);
        ushort4 o;
        o.x = f2bf(v.x); o.y = f2bf(v.y); o.z = f2bf(v.z); o.w = f2bf(v.w);
        *(ushort4*)(xB + ((size_t)t * BB + b) * FF + f4) = o;
    }
}

__global__ __launch_bounds__(256) void k_wcast(const float* __restrict__ in,
                                               unsigned short* __restrict__ out,
                                               int n4) {
    int stride = gridDim.x * 256;
    for (int i = blockIdx.x * 256 + threadIdx.x; i < n4; i += stride) {
        float4 v = ((const float4*)in)[i];
        ushort4 o;
        o.x = f2bf(v.x); o.y = f2bf(v.y); o.z = f2bf(v.z); o.w = f2bf(v.w);
        ((ushort4*)out)[i] = o;
    }
}

// ---------------------------------------------------------------------------
// Grid barrier: monotonic counter, one arrival per block. __threadfence() on
// both sides = agent-scope release/acquire (L2 writeback + invalidate), which
// is what makes cross-XCD h-handoff coherent (guide §6 G16).
// ---------------------------------------------------------------------------
__device__ __forceinline__ void gbar(unsigned* bar) {
    __syncthreads();                       // drains vmcnt: h-stores are in L2
    if (threadIdx.x == 0) {
        __threadfence();                   // release: flush L2 to coherence pt
        unsigned ticket = __hip_atomic_fetch_add(bar, 1u, __ATOMIC_RELAXED,
                                                 __HIP_MEMORY_SCOPE_AGENT);
        unsigned target = (ticket & ~(unsigned)(NBLK - 1)) + NBLK;
        while (__hip_atomic_load(bar, __ATOMIC_RELAXED,
                                 __HIP_MEMORY_SCOPE_AGENT) < target)
            __builtin_amdgcn_s_sleep(2);
        __threadfence();                   // acquire: invalidate stale lines
    }
    __syncthreads();
}

// ---------------------------------------------------------------------------
// One LSTM step, weights already LDS-resident in MFMA fragment order.
// Identical math/mapping to the verified k_step_lds epilogue; c is the
// caller's register (persistent across all 1024 steps).
// ---------------------------------------------------------------------------
template <int NCH>
__device__ __forceinline__ void lstm_step(
    const short8* __restrict__ sW,
    const unsigned short* __restrict__ A1, int K1,
    const unsigned short* __restrict__ A2, int K2, int C1,
    const f32x4 bias, float& creg,
    unsigned short* __restrict__ hOut,        // [BB][HH] bf16 recurrence
    float* __restrict__ tF,                   // [HH][BB] fp32 out-proj (or 0)
    unsigned short* __restrict__ tB,          // [HH][BB] bf16 out-proj (or 0)
    int lane, int q, int u, int b)
{
    short8 av[3][8];
    auto aload = [&](short8* dst, int c) {
        const unsigned short* ap = (c < C1)
            ? A1 + (size_t)b * K1 + (size_t)c * 256
            : A2 + (size_t)b * K2 + (size_t)(c - C1) * 256;
        ap += q * 8;
        #pragma unroll
        for (int f = 0; f < 8; ++f) dst[f] = *(const short8*)(ap + f * 32);
    };
    aload(av[0], 0);
    if (NCH > 1) aload(av[1], 1);

    f32x4 accA = {0.f, 0.f, 0.f, 0.f};
    f32x4 accB = {0.f, 0.f, 0.f, 0.f};
    #pragma unroll
    for (int c = 0; c < NCH; ++c) {
        if (c + 2 < NCH) aload(av[(c + 2) % 3], c + 2);
        const short8* cur = av[c % 3];
        #pragma unroll
        for (int f = 0; f < 8; ++f) {
            short8 wv = sW[(c * 8 + f) * 64 + lane];
            if (f & 1) accB = __builtin_amdgcn_mfma_f32_16x16x32_bf16(wv, cur[f], accB, 0, 0, 0);
            else       accA = __builtin_amdgcn_mfma_f32_16x16x32_bf16(wv, cur[f], accA, 0, 0, 0);
        }
    }
    f32x4 acc = accA + accB;

    float pi = acc[0] + bias[0];
    float pf = acc[1] + bias[1];
    float pg = acc[2] + bias[2];
    float po = acc[3] + bias[3];
    float iv = 1.f / (1.f + __expf(-pi));
    float fv = 1.f / (1.f + __expf(-pf));
    float gv = tanhf(pg);
    float ov = 1.f / (1.f + __expf(-po));
    float cn = fv * creg + iv * gv;
    creg = cn;
    float hn = ov * tanhf(cn);
    hOut[(size_t)b * HH + u] = f2bf(hn);
    if (tF) tF[(size_t)u * BB + b] = hn;
    if (tB) tB[(size_t)u * BB + b] = f2bf(hn);
}

// ---------------------------------------------------------------------------
// Persistent kernel: all 512 encoder + 512 decoder steps. 256 blocks (4
// hidden units each) x 4 waves (batch tiles). Weights staged to LDS ONCE
// (40KB enc + 64KB dec = 104KB). Cell state c lives in one register per
// thread the whole time (decoder c0 = encoder c_T falls out for free).
// ---------------------------------------------------------------------------
__global__ __launch_bounds__(256, 1) void k_lstm_persist(
    const unsigned short* __restrict__ xB,     // [TT][BB][FF]
    const unsigned short* __restrict__ WihE,   // [4H][FF] bf16
    const unsigned short* __restrict__ WhhE,   // [4H][HH] bf16
    const float* __restrict__ bE,
    const unsigned short* __restrict__ WihD,   // [4H][HH] bf16
    const unsigned short* __restrict__ WhhD,   // [4H][HH] bf16
    const float* __restrict__ bD,
    unsigned short* __restrict__ encB,         // [TT][BB][HH] bf16
    unsigned short* __restrict__ dech0,        // [BB][HH] bf16 ping
    unsigned short* __restrict__ dech1,        // [BB][HH] bf16 pong
    float* __restrict__ decTf,                 // [TT][HH][BB] fp32 or null
    unsigned short* __restrict__ decTb,        // [TT][HH][BB] bf16 or null
    unsigned* __restrict__ bar)
{
    __shared__ short8 sWe[NCHE * 8 * 64];      // 40KB
    __shared__ short8 sWd[NCHD * 8 * 64];      // 64KB

    const int tid  = threadIdx.x;
    const int lane = tid & 63;
    const int w    = tid >> 6;
    const int q    = lane >> 4;
    const int n    = lane & 15;
    const int j0   = blockIdx.x * 4;
    const int rrow = (n & 3) * HH + j0 + (n >> 2);
    const size_t SB = (size_t)BB * HH;

    // ---- stage BOTH weight sets into LDS, fragment order (once) ----
    #pragma unroll
    for (int i = 0; i < 2 * NCHE; ++i) {
        int g = i * 4 + w;                     // frag id 0..NCHE*8-1
        int c = g >> 3, f = g & 7;
        const unsigned short* Wp; int Ks; int cl;
        if (c < 1) { Wp = WihE; Ks = FF; cl = c; }
        else       { Wp = WhhE; Ks = HH; cl = c - 1; }
        sWe[g * 64 + lane] =
            *(const short8*)(Wp + (size_t)rrow * Ks + (size_t)cl * 256 + f * 32 + q * 8);
    }
    #pragma unroll
    for (int i = 0; i < 2 * NCHD; ++i) {
        int g = i * 4 + w;
        int c = g >> 3, f = g & 7;
        const unsigned short* Wp; int cl;
        if (c < 4) { Wp = WihD; cl = c; }
        else       { Wp = WhhD; cl = c - 4; }
        sWd[g * 64 + lane] =
            *(const short8*)(Wp + (size_t)rrow * HH + (size_t)cl * 256 + f * 32 + q * 8);
    }
    __syncthreads();

    const int u = j0 + q;
    const int b = w * 16 + n;
    const f32x4 biasE = {bE[u], bE[HH + u], bE[2 * HH + u], bE[3 * HH + u]};
    const f32x4 biasD = {bD[u], bD[HH + u], bD[2 * HH + u], bD[3 * HH + u]};

    float creg = 0.f;

    // ---- encoder: t=0 (h0=0 -> x-chunk only), then full steps ----
    lstm_step<1>(sWe, xB, FF, xB, FF, 1, biasE, creg,
                 encB, (float*)0, (unsigned short*)0, lane, q, u, b);
    gbar(bar);
    for (int t = 1; t < TT; ++t) {
        lstm_step<NCHE>(sWe, xB + (size_t)t * BB * FF, FF,
                        encB + (size_t)(t - 1) * SB, HH, 1,
                        biasE, creg, encB + (size_t)t * SB,
                        (float*)0, (unsigned short*)0, lane, q, u, b);
        gbar(bar);
    }

    // ---- decoder: h0 = enc h_T (encB[TT-1]), c continues in creg ----
    for (int t = 0; t < TT; ++t) {
        const unsigned short* A2 = (t == 0) ? encB + (size_t)(TT - 1) * SB
                                            : ((t & 1) ? dech1 : dech0);
        unsigned short* hOut = ((t + 1) & 1) ? dech1 : dech0;
        lstm_step<NCHD>(sWd, encB + (size_t)t * SB, HH, A2, HH, 4,
                        biasD, creg, hOut,
                        decTf ? decTf + (size_t)t * SB : (float*)0,
                        decTb ? decTb + (size_t)t * SB : (unsigned short*)0,
                        lane, q, u, b);
        if (t != TT - 1) gbar(bar);            // last step: kernel end syncs
    }
}

// ---------------------------------------------------------------------------
// LDS-staged MFMA LSTM step (verified round-4 kernel) — FALLBACK path only.
// ---------------------------------------------------------------------------
template <int NCH>
__global__ __launch_bounds__(256) void k_step_lds(
    const unsigned short* __restrict__ A1, const unsigned short* __restrict__ W1, int K1,
    const unsigned short* __restrict__ A2, const unsigned short* __restrict__ W2, int K2,
    int C1,
    const float* __restrict__ bias,
    float* __restrict__ Cbuf,
    unsigned short* __restrict__ hOut,
    float* __restrict__ chunkOut)
{
    __shared__ short8 sW[NCH * 8 * 64];

    const int tid  = threadIdx.x;
    const int lane = tid & 63;
    const int w    = tid >> 6;
    const int q    = lane >> 4;
    const int n    = lane & 15;
    const int j0   = blockIdx.x * 4;
    const int rrow = (n & 3) * HH + j0 + (n >> 2);

    short8 av[3][8];

    auto aload = [&](short8* dst, int c) {
        const unsigned short* ap = (c < C1)
            ? A1 + (size_t)(w * 16 + n) * K1 + (size_t)c * 256
            : A2 + (size_t)(w * 16 + n) * K2 + (size_t)(c - C1) * 256;
        ap += q * 8;
        #pragma unroll
        for (int f = 0; f < 8; ++f) dst[f] = *(const short8*)(ap + f * 32);
    };

    aload(av[0], 0);
    if (NCH > 1) aload(av[1], 1);

    #pragma unroll
    for (int i = 0; i < 2 * NCH; ++i) {
        int g = i * 4 + w;
        int c = g >> 3, f = g & 7;
        const unsigned short* Wp; int Ks; int cl;
        if (c < C1) { Wp = W1; Ks = K1; cl = c; }
        else        { Wp = W2; Ks = K2; cl = c - C1; }
        sW[g * 64 + lane] =
            *(const short8*)(Wp + (size_t)rrow * Ks + (size_t)cl * 256 + f * 32 + q * 8);
    }
    __syncthreads();

    f32x4 accA = {0.f, 0.f, 0.f, 0.f};
    f32x4 accB = {0.f, 0.f, 0.f, 0.f};
    #pragma unroll
    for (int c = 0; c < NCH; ++c) {
        if (c + 2 < NCH) aload(av[(c + 2) % 3], c + 2);
        const short8* cur = av[c % 3];
        #pragma unroll
        for (int f = 0; f < 8; ++f) {
            short8 wv = sW[(c * 8 + f) * 64 + lane];
            if (f & 1) accB = __builtin_amdgcn_mfma_f32_16x16x32_bf16(wv, cur[f], accB, 0, 0, 0);
            else       accA = __builtin_amdgcn_mfma_f32_16x16x32_bf16(wv, cur[f], accA, 0, 0, 0);
        }
    }
    f32x4 acc = accA + accB;

    const int u = j0 + q;
    const int b = w * 16 + n;
    float pi = acc[0] + bias[u];
    float pf = acc[1] + bias[HH + u];
    float pg = acc[2] + bias[2 * HH + u];
    float po = acc[3] + bias[3 * HH + u];
    float iv = 1.f / (1.f + __expf(-pi));
    float fv = 1.f / (1.f + __expf(-pf));
    float gv = tanhf(pg);
    float ov = 1.f / (1.f + __expf(-po));
    size_t cix = (size_t)u * BB + b;
    float c  = Cbuf[cix];
    float cn = fv * c + iv * gv;
    Cbuf[cix] = cn;
    float hn = ov * tanhf(cn);
    hOut[(size_t)b * HH + u] = f2bf(hn);
    if (chunkOut) chunkOut[cix] = hn;
}

// ---------------------------------------------------------------------------
// Fallback step (fp32 weights in-kernel convert).
// ---------------------------------------------------------------------------
__device__ __forceinline__ void seg_f32(const unsigned short* __restrict__ ap0,
                                        const float* __restrict__ wp0,
                                        int nch, f32x4& acc) {
    const unsigned short* ap = ap0;
    const float* wp = wp0;
    #pragma unroll 2
    for (int c = 0; c < nch; ++c) {
        float4 wa = *(const float4*)wp;
        float4 wb = *(const float4*)(wp + 4);
        short8 av = *(const short8*)ap;
        short8 wv;
        wv[0] = (short)f2bf(wa.x); wv[1] = (short)f2bf(wa.y);
        wv[2] = (short)f2bf(wa.z); wv[3] = (short)f2bf(wa.w);
        wv[4] = (short)f2bf(wb.x); wv[5] = (short)f2bf(wb.y);
        wv[6] = (short)f2bf(wb.z); wv[7] = (short)f2bf(wb.w);
        acc = __builtin_amdgcn_mfma_f32_16x16x32_bf16(wv, av, acc, 0, 0, 0);
        ap += 32; wp += 32;
    }
}

__global__ __launch_bounds__(256) void k_step_f32w(
    const unsigned short* __restrict__ A1, const float* __restrict__ W1, int K1,
    const unsigned short* __restrict__ A2, const float* __restrict__ W2, int K2,
    const float* __restrict__ bias,
    float* __restrict__ Cbuf, unsigned short* __restrict__ hOut,
    float* __restrict__ chunkOut)
{
    const int tid  = threadIdx.x;
    const int lane = tid & 63;
    const int w    = tid >> 6;
    const int q    = lane >> 4;
    const int n    = lane & 15;
    const int j0   = blockIdx.x * 4;
    const int rrow = (n & 3) * HH + j0 + (n >> 2);

    f32x4 acc = {0.f, 0.f, 0.f, 0.f};
    seg_f32(A1 + (size_t)(w * 16 + n) * K1 + q * 8,
            W1 + (size_t)rrow * K1 + q * 8, K1 >> 5, acc);
    if (K2)
        seg_f32(A2 + (size_t)(w * 16 + n) * HH + q * 8,
                W2 + (size_t)rrow * HH + q * 8, HH >> 5, acc);

    const int u = j0 + q;
    const int b = w * 16 + n;
    float pi = acc[0] + bias[u];
    float pf = acc[1] + bias[HH + u];
    float pg = acc[2] + bias[2 * HH + u];
    float po = acc[3] + bias[3 * HH + u];
    float iv = 1.f / (1.f + __expf(-pi));
    float fv = 1.f / (1.f + __expf(-pf));
    float gv = tanhf(pg);
    float ov = 1.f / (1.f + __expf(-po));
    size_t cix = (size_t)u * BB + b;
    float c  = Cbuf[cix];
    float cn = fv * c + iv * gv;
    Cbuf[cix] = cn;
    float hn = ov * tanhf(cn);
    hOut[(size_t)b * HH + u] = f2bf(hn);
    if (chunkOut) chunkOut[cix] = hn;
}

// ---------------------------------------------------------------------------
// Output projection, fp32 input (round-2 proven kernel).
// ---------------------------------------------------------------------------
__global__ __launch_bounds__(256) void k_out_proj(
    const float* __restrict__ chunk,  // [C][HH][BB]
    const float* __restrict__ Wout,   // [FF][HH]
    const float* __restrict__ bout,   // [FF]
    float* __restrict__ out,          // [BB][TT][FF]
    int t0)
{
    int tl = blockIdx.x;
    int t  = t0 + tl;
    int fg = blockIdx.y;
    const int lane = threadIdx.x & 63;
    const int wv   = __builtin_amdgcn_readfirstlane(threadIdx.x >> 6);
    const int f0   = fg * 64 + wv * 16;
    const float* a = chunk + (size_t)tl * HH * BB;

    float acc[16];
    #pragma unroll
    for (int i = 0; i < 16; ++i) acc[i] = bout[f0 + i];

    for (int k = 0; k < HH; k += 4) {
        #pragma unroll
        for (int u = 0; u < 4; ++u) {
            float hv = a[(size_t)(k + u) * BB + lane];
            #pragma unroll
            for (int i = 0; i < 16; ++i)
                acc[i] = fmaf(Wout[(size_t)(f0 + i) * HH + k + u], hv, acc[i]);
        }
    }

    float* op = out + ((size_t)lane * TT + t) * FF + f0;
    #pragma unroll
    for (int i = 0; i < 16; i += 4) {
        float4 v = make_float4(acc[i], acc[i + 1], acc[i + 2], acc[i + 3]);
        *(float4*)(op + i) = v;
    }
}

// Same, bf16 input (used when workspace only fits bf16 decoder history).
__global__ __launch_bounds__(256) void k_out_proj_bf(
    const unsigned short* __restrict__ decT,  // [TT][HH][BB] bf16
    const float* __restrict__ Wout,
    const float* __restrict__ bout,
    float* __restrict__ out)
{
    int t  = blockIdx.x;
    int fg = blockIdx.y;
    const int lane = threadIdx.x & 63;
    const int wv   = __builtin_amdgcn_readfirstlane(threadIdx.x >> 6);
    const int f0   = fg * 64 + wv * 16;
    const unsigned short* a = decT + (size_t)t * HH * BB;

    float acc[16];
    #pragma unroll
    for (int i = 0; i < 16; ++i) acc[i] = bout[f0 + i];

    for (int k = 0; k < HH; k += 4) {
        #pragma unroll
        for (int u = 0; u < 4; ++u) {
            float hv = bf2f(a[(size_t)(k + u) * BB + lane]);
            #pragma unroll
            for (int i = 0; i < 16; ++i)
                acc[i] = fmaf(Wout[(size_t)(f0 + i) * HH + k + u], hv, acc[i]);
        }
    }

    float* op = out + ((size_t)lane * TT + t) * FF + f0;
    #pragma unroll
    for (int i = 0; i < 16; i += 4) {
        float4 v = make_float4(acc[i], acc[i + 1], acc[i + 2], acc[i + 3]);
        *(float4*)(op + i) = v;
    }
}

// ---------------------------------------------------------------------------
extern "C" void kernel_launch(void* const* d_in, const int* in_sizes, int n_in,
                              void* d_out, int out_size, void* d_ws, size_t ws_size,
                              hipStream_t stream) {
    const float* x     = (const float*)d_in[0];
    const float* Wih_e = (const float*)d_in[1];
    const float* Whh_e = (const float*)d_in[2];
    const float* b_e   = (const float*)d_in[3];
    const float* Wih_d = (const float*)d_in[4];
    const float* Whh_d = (const float*)d_in[5];
    const float* b_d   = (const float*)d_in[6];
    const float* Wout  = (const float*)d_in[7];
    const float* bout  = (const float*)d_in[8];
    float* out = (float*)d_out;

    const size_t SB = (size_t)BB * HH;            // 65536 elems per state

    unsigned short* xB = (unsigned short*)d_out;  // [TT][BB][FF] bf16

    // ================= persistent-kernel tier =================
    {
        char* p = (char*)d_ws;
        unsigned* bar = (unsigned*)p; p += 256;
        unsigned short* encB  = (unsigned short*)p; p += (size_t)TT * SB * 2;
        unsigned short* dech0 = (unsigned short*)p; p += SB * 2;
        unsigned short* dech1 = (unsigned short*)p; p += SB * 2;
        unsigned short* WihEb = (unsigned short*)p; p += (size_t)4 * HH * FF * 2;
        unsigned short* WhhEb = (unsigned short*)p; p += (size_t)4 * HH * HH * 2;
        unsigned short* WihDb = (unsigned short*)p; p += (size_t)4 * HH * HH * 2;
        unsigned short* WhhDb = (unsigned short*)p; p += (size_t)4 * HH * HH * 2;
        size_t base = (size_t)(p - (char*)d_ws);

        float* decTf = 0; unsigned short* decTb = 0;
        if      (ws_size >= base + (size_t)TT * SB * 4) decTf = (float*)p;
        else if (ws_size >= base + (size_t)TT * SB * 2) decTb = (unsigned short*)p;

        if (decTf || decTb) {
            hipMemsetAsync(bar, 0, 4, stream);
            k_cast_x<<<TT, 256, 0, stream>>>(x, xB);
            k_wcast<<<1024, 256, 0, stream>>>(Wih_e, WihEb, 4 * HH * FF / 4);
            k_wcast<<<1024, 256, 0, stream>>>(Whh_e, WhhEb, 4 * HH * HH / 4);
            k_wcast<<<1024, 256, 0, stream>>>(Wih_d, WihDb, 4 * HH * HH / 4);
            k_wcast<<<1024, 256, 0, stream>>>(Whh_d, WhhDb, 4 * HH * HH / 4);

            void* args[] = {
                (void*)&xB, (void*)&WihEb, (void*)&WhhEb, (void*)&b_e,
                (void*)&WihDb, (void*)&WhhDb, (void*)&b_d,
                (void*)&encB, (void*)&dech0, (void*)&dech1,
                (void*)&decTf, (void*)&decTb, (void*)&bar};
            hipLaunchCooperativeKernel((const void*)k_lstm_persist,
                                       dim3(NBLK), dim3(256), args, 0, stream);

            if (decTf)
                k_out_proj<<<dim3(TT, 4), 256, 0, stream>>>(decTf, Wout, bout, out, 0);
            else
                k_out_proj_bf<<<dim3(TT, 4), 256, 0, stream>>>(decTb, Wout, bout, out);
            return;
        }
    }

    // ================= fallback: previous verified path =================
    char* p = (char*)d_ws;
    unsigned short* encB  = (unsigned short*)p; p += (size_t)TT * SB * 2;
    unsigned short* dech0 = (unsigned short*)p; p += SB * 2;
    unsigned short* dech1 = (unsigned short*)p; p += SB * 2;
    float* cbuf = (float*)p; p += SB * 4;
    size_t used  = (size_t)(p - (char*)d_ws);
    size_t avail = ws_size > used ? ws_size - used : 0;

    const size_t WE_B = ((size_t)4 * HH * FF + (size_t)4 * HH * HH) * 2;
    const size_t WD_B = ((size_t)4 * HH * HH) * 2 * 2;
    const size_t CH8  = (size_t)8 * SB * 4;

    bool wbAll = (avail >= WE_B + WD_B + CH8);
    bool wbEnc = wbAll || (avail >= WE_B + CH8);

    unsigned short *WihEb = 0, *WhhEb = 0, *WihDb = 0, *WhhDb = 0;
    if (wbEnc) {
        WihEb = (unsigned short*)p; p += (size_t)4 * HH * FF * 2;
        WhhEb = (unsigned short*)p; p += (size_t)4 * HH * HH * 2;
        avail -= WE_B;
    }
    if (wbAll) {
        WihDb = (unsigned short*)p; p += (size_t)4 * HH * HH * 2;
        WhhDb = (unsigned short*)p; p += (size_t)4 * HH * HH * 2;
        avail -= WD_B;
    }
    int C = 8;
    if      (avail >= (size_t)64 * SB * 4) C = 64;
    else if (avail >= (size_t)32 * SB * 4) C = 32;
    else if (avail >= (size_t)16 * SB * 4) C = 16;
    float* chunk = (float*)p;

    hipMemsetAsync(cbuf, 0, SB * 4, stream);
    k_cast_x<<<TT, 256, 0, stream>>>(x, xB);
    if (wbEnc) {
        k_wcast<<<1024, 256, 0, stream>>>(Wih_e, WihEb, 4 * HH * FF / 4);
        k_wcast<<<1024, 256, 0, stream>>>(Whh_e, WhhEb, 4 * HH * HH / 4);
    }
    if (wbAll) {
        k_wcast<<<1024, 256, 0, stream>>>(Wih_d, WihDb, 4 * HH * HH / 4);
        k_wcast<<<1024, 256, 0, stream>>>(Whh_d, WhhDb, 4 * HH * HH / 4);
    }

    for (int t = 0; t < TT; ++t) {
        const unsigned short* A1 = xB + (size_t)t * BB * FF;
        const unsigned short* A2 = t ? encB + (size_t)(t - 1) * SB : (unsigned short*)0;
        unsigned short* hOut = encB + (size_t)t * SB;
        if (wbEnc) {
            if (t == 0)
                k_step_lds<1><<<256, 256, 0, stream>>>(A1, WihEb, FF, A2, WhhEb, HH,
                                                       1, b_e, cbuf, hOut, (float*)0);
            else
                k_step_lds<5><<<256, 256, 0, stream>>>(A1, WihEb, FF, A2, WhhEb, HH,
                                                       1, b_e, cbuf, hOut, (float*)0);
        } else {
            k_step_f32w<<<256, 256, 0, stream>>>(A1, Wih_e, FF, A2, Whh_e,
                                                 t ? HH : 0, b_e, cbuf, hOut, (float*)0);
        }
    }

    for (int t = 0; t < TT; ++t) {
        const unsigned short* A1 = encB + (size_t)t * SB;
        const unsigned short* A2 = (t == 0) ? encB + (size_t)(TT - 1) * SB
                                            : ((t & 1) ? dech1 : dech0);
        unsigned short* hOut = ((t + 1) & 1) ? dech1 : dech0;
        int l = t & (C - 1);
        float* ch = chunk + (size_t)l * SB;
        if (wbAll)
            k_step_lds<8><<<256, 256, 0, stream>>>(A1, WihDb, HH, A2, WhhDb, HH,
                                                   4, b_d, cbuf, hOut, ch);
        else
            k_step_f32w<<<256, 256, 0, stream>>>(A1, Wih_d, FF, A2, Whh_d, HH,
                                                 b_d, cbuf, hOut, ch);
        if (l == C - 1)
            k_out_proj<<<dim3(C, 4), 256, 0, stream>>>(chunk, Wout, bout, out,
                                                       t - (C - 1));
    }
}

// Round 2
// 10594.492 us; speedup vs baseline: 2.6707x; 2.6707x over previous
//
#include <hip/hip_runtime.h>
#include <math.h>

#define TT 512
#define BB 64
#define FF 256
#define HH 1024
#define NBLK 256
#define NCHE 5   // encoder K-chunks: 256 (x) + 4*256 (h)
#define NCHD 8   // decoder K-chunks: 4*256 (enc h) + 4*256 (dec h)
#define NGRP 16  // barrier arrival groups (distinct cache lines)

typedef __attribute__((ext_vector_type(8))) short short8;
typedef __attribute__((ext_vector_type(4))) float f32x4;

__device__ __forceinline__ unsigned short f2bf(float f) {
    unsigned u = __float_as_uint(f);
    u += 0x7FFFu + ((u >> 16) & 1u);   // RNE (finite inputs only)
    return (unsigned short)(u >> 16);
}
__device__ __forceinline__ float bf2f(unsigned short u) {
    return __uint_as_float((unsigned)u << 16);
}

// ---------------------------------------------------------------------------
// x[b][t][f] fp32 -> xB[t][b][f] bf16 (batch-major per step). xB lives in
// d_out (dead until out_proj overwrites it).
// ---------------------------------------------------------------------------
__global__ __launch_bounds__(256) void k_cast_x(const float* __restrict__ x,
                                                unsigned short* __restrict__ xB) {
    int t = blockIdx.x;
    #pragma unroll
    for (int i = 0; i < 16; ++i) {
        int id = threadIdx.x + i * 256;
        int b  = id >> 6;
        int f4 = (id & 63) << 2;
        float4 v = *(const float4*)(x + ((size_t)b * TT + t) * FF + f4);
        ushort4 o;
        o.x = f2bf(v.x); o.y = f2bf(v.y); o.z = f2bf(v.z); o.w = f2bf(v.w);
        *(ushort4*)(xB + ((size_t)t * BB + b) * FF + f4) = o;
    }
}

__global__ __launch_bounds__(256) void k_wcast(const float* __restrict__ in,
                                               unsigned short* __restrict__ out,
                                               int n4) {
    int stride = gridDim.x * 256;
    for (int i = blockIdx.x * 256 + threadIdx.x; i < n4; i += stride) {
        float4 v = ((const float4*)in)[i];
        ushort4 o;
        o.x = f2bf(v.x); o.y = f2bf(v.y); o.z = f2bf(v.z); o.w = f2bf(v.w);
        ((ushort4*)out)[i] = o;
    }
}

// ---------------------------------------------------------------------------
// Grid barrier, round-2 redesign.
//  * Two-level arrival: 16 group counters (128B-spaced lines) -> root -> flag.
//    Removes the 256-way RMW serialization on one line (round-1: ~26us).
//  * Release-only ordering: __builtin_amdgcn_fence(RELEASE, "agent") emits
//    buffer_wbl2 (flush dirty h-stores to coherence point) WITHOUT buffer_inv.
//    Safe because every cross-phase buffer is write-once fresh-address
//    (encB[t] ring, decR[t] ring): consumers can never hold a stale line.
//  * All signaling uses atomic RMW / atomic load only — the primitive class
//    round 1 already proved coherent across XCDs.
// ---------------------------------------------------------------------------
__device__ __forceinline__ void gbar2(unsigned* __restrict__ bar, int phase) {
    __syncthreads();                     // drains this block's h-stores (vmcnt)
    if (threadIdx.x == 0) {
        const unsigned GSZ = NBLK / NGRP;
        unsigned g = (unsigned)blockIdx.x & (NGRP - 1);
        __builtin_amdgcn_fence(__ATOMIC_RELEASE, "agent");   // wbl2, no inv
        unsigned t = __hip_atomic_fetch_add(bar + g * 32, 1u,
                                            __ATOMIC_RELAXED, __HIP_MEMORY_SCOPE_AGENT);
        if (t == (unsigned)phase * GSZ + GSZ - 1) {
            unsigned r = __hip_atomic_fetch_add(bar + NGRP * 32, 1u,
                                                __ATOMIC_RELAXED, __HIP_MEMORY_SCOPE_AGENT);
            if (r == (unsigned)phase * NGRP + NGRP - 1)
                __hip_atomic_fetch_add(bar + NGRP * 32 + 32, 1u,
                                       __ATOMIC_RELAXED, __HIP_MEMORY_SCOPE_AGENT);
        }
        while (__hip_atomic_load(bar + NGRP * 32 + 32, __ATOMIC_RELAXED,
                                 __HIP_MEMORY_SCOPE_AGENT) < (unsigned)(phase + 1))
            __builtin_amdgcn_s_sleep(2);
    }
    __syncthreads();
}

// ---------------------------------------------------------------------------
// One LSTM step, weights LDS-resident in MFMA fragment order. NPRE A1 chunks
// (recurrence-independent data) are prefetched BEFORE the barrier so their
// latency hides under the barrier wait. A2 (h_{t-1}) chunks load after.
// Math/mapping identical to the verified round-4 kernel.
// ---------------------------------------------------------------------------
template <int NCH, int NPRE>
__device__ __forceinline__ void lstm_step(
    const short8* __restrict__ sW,
    const unsigned short* __restrict__ A1, int K1,
    const unsigned short* __restrict__ A2, int K2, int C1,
    const f32x4 bias, float& creg,
    unsigned short* __restrict__ hOut,        // [BB][HH] bf16 (fresh ring slot)
    unsigned* __restrict__ bar, int phase,
    int lane, int q, int u, int b)
{
    short8 av[3][8];
    auto aload = [&](short8* dst, int c) {
        const unsigned short* ap = (c < C1)
            ? A1 + (size_t)b * K1 + (size_t)c * 256
            : A2 + (size_t)b * K2 + (size_t)(c - C1) * 256;
        ap += q * 8;
        #pragma unroll
        for (int f = 0; f < 8; ++f) dst[f] = *(const short8*)(ap + f * 32);
    };

    // prefetch recurrence-independent chunks (overlap the barrier)
    aload(av[0], 0);
    if (NCH > 1 && NPRE > 1) aload(av[1], 1);

    if (phase >= 0) gbar2(bar, phase);

    if (NCH > 1 && NPRE <= 1) aload(av[1], 1);

    f32x4 accA = {0.f, 0.f, 0.f, 0.f};
    f32x4 accB = {0.f, 0.f, 0.f, 0.f};
    #pragma unroll
    for (int c = 0; c < NCH; ++c) {
        if (c + 2 < NCH) aload(av[(c + 2) % 3], c + 2);
        const short8* cur = av[c % 3];
        #pragma unroll
        for (int f = 0; f < 8; ++f) {
            short8 wv = sW[(c * 8 + f) * 64 + lane];
            if (f & 1) accB = __builtin_amdgcn_mfma_f32_16x16x32_bf16(wv, cur[f], accB, 0, 0, 0);
            else       accA = __builtin_amdgcn_mfma_f32_16x16x32_bf16(wv, cur[f], accA, 0, 0, 0);
        }
    }
    f32x4 acc = accA + accB;

    float pi = acc[0] + bias[0];
    float pf = acc[1] + bias[1];
    float pg = acc[2] + bias[2];
    float po = acc[3] + bias[3];
    float iv = 1.f / (1.f + __expf(-pi));
    float fv = 1.f / (1.f + __expf(-pf));
    float gv = tanhf(pg);
    float ov = 1.f / (1.f + __expf(-po));
    float cn = fv * creg + iv * gv;
    creg = cn;
    float hn = ov * tanhf(cn);
    hOut[(size_t)b * HH + u] = f2bf(hn);
}

// ---------------------------------------------------------------------------
// Persistent kernel: all 512 encoder + 512 decoder steps. 256 blocks (4
// hidden units each) x 4 waves (batch tiles). Weights staged to LDS ONCE
// (40KB enc + 64KB dec = 104KB). Cell state c lives in one register per
// thread (decoder c0 = encoder c_T falls out for free). Decoder h goes into
// a fresh ring slot decR[t] each step (no stale-line hazard, and decR doubles
// as the out_proj input).
// ---------------------------------------------------------------------------
__global__ __launch_bounds__(256, 1) void k_lstm_persist(
    const unsigned short* __restrict__ xB,     // [TT][BB][FF]
    const unsigned short* __restrict__ WihE,   // [4H][FF] bf16
    const unsigned short* __restrict__ WhhE,   // [4H][HH] bf16
    const float* __restrict__ bE,
    const unsigned short* __restrict__ WihD,   // [4H][HH] bf16
    const unsigned short* __restrict__ WhhD,   // [4H][HH] bf16
    const float* __restrict__ bD,
    unsigned short* __restrict__ encB,         // [TT][BB][HH] bf16 ring
    unsigned short* __restrict__ decR,         // [TT][BB][HH] bf16 ring
    unsigned* __restrict__ bar)
{
    __shared__ short8 sWe[NCHE * 8 * 64];      // 40KB
    __shared__ short8 sWd[NCHD * 8 * 64];      // 64KB

    const int tid  = threadIdx.x;
    const int lane = tid & 63;
    const int w    = tid >> 6;
    const int q    = lane >> 4;
    const int n    = lane & 15;
    const int j0   = blockIdx.x * 4;
    const int rrow = (n & 3) * HH + j0 + (n >> 2);
    const size_t SB = (size_t)BB * HH;

    // ---- stage BOTH weight sets into LDS, fragment order (once) ----
    #pragma unroll
    for (int i = 0; i < 2 * NCHE; ++i) {
        int g = i * 4 + w;                     // frag id 0..NCHE*8-1
        int c = g >> 3, f = g & 7;
        const unsigned short* Wp; int Ks; int cl;
        if (c < 1) { Wp = WihE; Ks = FF; cl = c; }
        else       { Wp = WhhE; Ks = HH; cl = c - 1; }
        sWe[g * 64 + lane] =
            *(const short8*)(Wp + (size_t)rrow * Ks + (size_t)cl * 256 + f * 32 + q * 8);
    }
    #pragma unroll
    for (int i = 0; i < 2 * NCHD; ++i) {
        int g = i * 4 + w;
        int c = g >> 3, f = g & 7;
        const unsigned short* Wp; int cl;
        if (c < 4) { Wp = WihD; cl = c; }
        else       { Wp = WhhD; cl = c - 4; }
        sWd[g * 64 + lane] =
            *(const short8*)(Wp + (size_t)rrow * HH + (size_t)cl * 256 + f * 32 + q * 8);
    }
    __syncthreads();

    const int u = j0 + q;
    const int b = w * 16 + n;
    const f32x4 biasE = {bE[u], bE[HH + u], bE[2 * HH + u], bE[3 * HH + u]};
    const f32x4 biasD = {bD[u], bD[HH + u], bD[2 * HH + u], bD[3 * HH + u]};

    float creg = 0.f;

    // ---- encoder: t=0 (h0=0 -> x-chunk only, no barrier yet) ----
    lstm_step<1, 1>(sWe, xB, FF, xB, FF, 1, biasE, creg,
                    encB, bar, -1, lane, q, u, b);
    for (int t = 1; t < TT; ++t) {
        lstm_step<NCHE, 1>(sWe, xB + (size_t)t * BB * FF, FF,
                           encB + (size_t)(t - 1) * SB, HH, 1,
                           biasE, creg, encB + (size_t)t * SB,
                           bar, t - 1, lane, q, u, b);
    }

    // ---- decoder: h0 = enc h_T (encB[TT-1]), c continues in creg ----
    for (int t = 0; t < TT; ++t) {
        const unsigned short* A2 = (t == 0) ? encB + (size_t)(TT - 1) * SB
                                            : decR + (size_t)(t - 1) * SB;
        lstm_step<NCHD, 2>(sWd, encB + (size_t)t * SB, HH, A2, HH, 4,
                           biasD, creg, decR + (size_t)t * SB,
                           bar, (TT - 1) + t, lane, q, u, b);
    }
    // kernel-end release flushes decR for the out_proj dispatch
}

// ---------------------------------------------------------------------------
// Output projection from the bf16 decoder ring decR [TT][BB][HH].
// lane = batch; each lane streams its own row with short8 loads; Wout
// accesses are lane-uniform (scalar path).
// ---------------------------------------------------------------------------
__global__ __launch_bounds__(256) void k_out_proj_r(
    const unsigned short* __restrict__ decR,  // [TT][BB][HH]
    const float* __restrict__ Wout,           // [FF][HH]
    const float* __restrict__ bout,           // [FF]
    float* __restrict__ out)                  // [BB][TT][FF]
{
    int t  = blockIdx.x;
    int fg = blockIdx.y;
    const int lane = threadIdx.x & 63;
    const int wv   = __builtin_amdgcn_readfirstlane(threadIdx.x >> 6);
    const int f0   = fg * 64 + wv * 16;
    const unsigned short* a = decR + ((size_t)t * BB + lane) * HH;

    float acc[16];
    #pragma unroll
    for (int i = 0; i < 16; ++i) acc[i] = bout[f0 + i];

    for (int k8 = 0; k8 < HH / 8; ++k8) {
        short8 hv8 = *(const short8*)(a + k8 * 8);
        #pragma unroll
        for (int uu = 0; uu < 8; ++uu) {
            float hv = bf2f((unsigned short)hv8[uu]);
            #pragma unroll
            for (int i = 0; i < 16; ++i)
                acc[i] = fmaf(Wout[(size_t)(f0 + i) * HH + k8 * 8 + uu], hv, acc[i]);
        }
    }

    float* op = out + ((size_t)lane * TT + t) * FF + f0;
    #pragma unroll
    for (int i = 0; i < 16; i += 4) {
        float4 v = make_float4(acc[i], acc[i + 1], acc[i + 2], acc[i + 3]);
        *(float4*)(op + i) = v;
    }
}

// ---------------------------------------------------------------------------
// FALLBACK path (small workspace): round-4 verified per-step kernels.
// ---------------------------------------------------------------------------
template <int NCH>
__global__ __launch_bounds__(256) void k_step_lds(
    const unsigned short* __restrict__ A1, const unsigned short* __restrict__ W1, int K1,
    const unsigned short* __restrict__ A2, const unsigned short* __restrict__ W2, int K2,
    int C1,
    const float* __restrict__ bias,
    float* __restrict__ Cbuf,
    unsigned short* __restrict__ hOut,
    float* __restrict__ chunkOut)
{
    __shared__ short8 sW[NCH * 8 * 64];

    const int tid  = threadIdx.x;
    const int lane = tid & 63;
    const int w    = tid >> 6;
    const int q    = lane >> 4;
    const int n    = lane & 15;
    const int j0   = blockIdx.x * 4;
    const int rrow = (n & 3) * HH + j0 + (n >> 2);

    short8 av[3][8];

    auto aload = [&](short8* dst, int c) {
        const unsigned short* ap = (c < C1)
            ? A1 + (size_t)(w * 16 + n) * K1 + (size_t)c * 256
            : A2 + (size_t)(w * 16 + n) * K2 + (size_t)(c - C1) * 256;
        ap += q * 8;
        #pragma unroll
        for (int f = 0; f < 8; ++f) dst[f] = *(const short8*)(ap + f * 32);
    };

    aload(av[0], 0);
    if (NCH > 1) aload(av[1], 1);

    #pragma unroll
    for (int i = 0; i < 2 * NCH; ++i) {
        int g = i * 4 + w;
        int c = g >> 3, f = g & 7;
        const unsigned short* Wp; int Ks; int cl;
        if (c < C1) { Wp = W1; Ks = K1; cl = c; }
        else        { Wp = W2; Ks = K2; cl = c - C1; }
        sW[g * 64 + lane] =
            *(const short8*)(Wp + (size_t)rrow * Ks + (size_t)cl * 256 + f * 32 + q * 8);
    }
    __syncthreads();

    f32x4 accA = {0.f, 0.f, 0.f, 0.f};
    f32x4 accB = {0.f, 0.f, 0.f, 0.f};
    #pragma unroll
    for (int c = 0; c < NCH; ++c) {
        if (c + 2 < NCH) aload(av[(c + 2) % 3], c + 2);
        const short8* cur = av[c % 3];
        #pragma unroll
        for (int f = 0; f < 8; ++f) {
            short8 wv = sW[(c * 8 + f) * 64 + lane];
            if (f & 1) accB = __builtin_amdgcn_mfma_f32_16x16x32_bf16(wv, cur[f], accB, 0, 0, 0);
            else       accA = __builtin_amdgcn_mfma_f32_16x16x32_bf16(wv, cur[f], accA, 0, 0, 0);
        }
    }
    f32x4 acc = accA + accB;

    const int u = j0 + q;
    const int b = w * 16 + n;
    float pi = acc[0] + bias[u];
    float pf = acc[1] + bias[HH + u];
    float pg = acc[2] + bias[2 * HH + u];
    float po = acc[3] + bias[3 * HH + u];
    float iv = 1.f / (1.f + __expf(-pi));
    float fv = 1.f / (1.f + __expf(-pf));
    float gv = tanhf(pg);
    float ov = 1.f / (1.f + __expf(-po));
    size_t cix = (size_t)u * BB + b;
    float c  = Cbuf[cix];
    float cn = fv * c + iv * gv;
    Cbuf[cix] = cn;
    float hn = ov * tanhf(cn);
    hOut[(size_t)b * HH + u] = f2bf(hn);
    if (chunkOut) chunkOut[cix] = hn;
}

__device__ __forceinline__ void seg_f32(const unsigned short* __restrict__ ap0,
                                        const float* __restrict__ wp0,
                                        int nch, f32x4& acc) {
    const unsigned short* ap = ap0;
    const float* wp = wp0;
    #pragma unroll 2
    for (int c = 0; c < nch; ++c) {
        float4 wa = *(const float4*)wp;
        float4 wb = *(const float4*)(wp + 4);
        short8 av = *(const short8*)ap;
        short8 wv;
        wv[0] = (short)f2bf(wa.x); wv[1] = (short)f2bf(wa.y);
        wv[2] = (short)f2bf(wa.z); wv[3] = (short)f2bf(wa.w);
        wv[4] = (short)f2bf(wb.x); wv[5] = (short)f2bf(wb.y);
        wv[6] = (short)f2bf(wb.z); wv[7] = (short)f2bf(wb.w);
        acc = __builtin_amdgcn_mfma_f32_16x16x32_bf16(wv, av, acc, 0, 0, 0);
        ap += 32; wp += 32;
    }
}

__global__ __launch_bounds__(256) void k_step_f32w(
    const unsigned short* __restrict__ A1, const float* __restrict__ W1, int K1,
    const unsigned short* __restrict__ A2, const float* __restrict__ W2, int K2,
    const float* __restrict__ bias,
    float* __restrict__ Cbuf, unsigned short* __restrict__ hOut,
    float* __restrict__ chunkOut)
{
    const int tid  = threadIdx.x;
    const int lane = tid & 63;
    const int w    = tid >> 6;
    const int q    = lane >> 4;
    const int n    = lane & 15;
    const int j0   = blockIdx.x * 4;
    const int rrow = (n & 3) * HH + j0 + (n >> 2);

    f32x4 acc = {0.f, 0.f, 0.f, 0.f};
    seg_f32(A1 + (size_t)(w * 16 + n) * K1 + q * 8,
            W1 + (size_t)rrow * K1 + q * 8, K1 >> 5, acc);
    if (K2)
        seg_f32(A2 + (size_t)(w * 16 + n) * HH + q * 8,
                W2 + (size_t)rrow * HH + q * 8, HH >> 5, acc);

    const int u = j0 + q;
    const int b = w * 16 + n;
    float pi = acc[0] + bias[u];
    float pf = acc[1] + bias[HH + u];
    float pg = acc[2] + bias[2 * HH + u];
    float po = acc[3] + bias[3 * HH + u];
    float iv = 1.f / (1.f + __expf(-pi));
    float fv = 1.f / (1.f + __expf(-pf));
    float gv = tanhf(pg);
    float ov = 1.f / (1.f + __expf(-po));
    size_t cix = (size_t)u * BB + b;
    float c  = Cbuf[cix];
    float cn = fv * c + iv * gv;
    Cbuf[cix] = cn;
    float hn = ov * tanhf(cn);
    hOut[(size_t)b * HH + u] = f2bf(hn);
    if (chunkOut) chunkOut[cix] = hn;
}

__global__ __launch_bounds__(256) void k_out_proj(
    const float* __restrict__ chunk,  // [C][HH][BB]
    const float* __restrict__ Wout,
    const float* __restrict__ bout,
    float* __restrict__ out,
    int t0)
{
    int tl = blockIdx.x;
    int t  = t0 + tl;
    int fg = blockIdx.y;
    const int lane = threadIdx.x & 63;
    const int wv   = __builtin_amdgcn_readfirstlane(threadIdx.x >> 6);
    const int f0   = fg * 64 + wv * 16;
    const float* a = chunk + (size_t)tl * HH * BB;

    float acc[16];
    #pragma unroll
    for (int i = 0; i < 16; ++i) acc[i] = bout[f0 + i];

    for (int k = 0; k < HH; k += 4) {
        #pragma unroll
        for (int u = 0; u < 4; ++u) {
            float hv = a[(size_t)(k + u) * BB + lane];
            #pragma unroll
            for (int i = 0; i < 16; ++i)
                acc[i] = fmaf(Wout[(size_t)(f0 + i) * HH + k + u], hv, acc[i]);
        }
    }

    float* op = out + ((size_t)lane * TT + t) * FF + f0;
    #pragma unroll
    for (int i = 0; i < 16; i += 4) {
        float4 v = make_float4(acc[i], acc[i + 1], acc[i + 2], acc[i + 3]);
        *(float4*)(op + i) = v;
    }
}

// ---------------------------------------------------------------------------
extern "C" void kernel_launch(void* const* d_in, const int* in_sizes, int n_in,
                              void* d_out, int out_size, void* d_ws, size_t ws_size,
                              hipStream_t stream) {
    const float* x     = (const float*)d_in[0];
    const float* Wih_e = (const float*)d_in[1];
    const float* Whh_e = (const float*)d_in[2];
    const float* b_e   = (const float*)d_in[3];
    const float* Wih_d = (const float*)d_in[4];
    const float* Whh_d = (const float*)d_in[5];
    const float* b_d   = (const float*)d_in[6];
    const float* Wout  = (const float*)d_in[7];
    const float* bout  = (const float*)d_in[8];
    float* out = (float*)d_out;

    const size_t SB = (size_t)BB * HH;            // 65536 elems per state

    unsigned short* xB = (unsigned short*)d_out;  // [TT][BB][FF] bf16

    // ================= persistent-kernel tier (~154MB ws) =================
    {
        char* p = (char*)d_ws;
        unsigned* bar = (unsigned*)p; p += 4096;
        unsigned short* encB  = (unsigned short*)p; p += (size_t)TT * SB * 2;   // 64MB
        unsigned short* decR  = (unsigned short*)p; p += (size_t)TT * SB * 2;   // 64MB
        unsigned short* WihEb = (unsigned short*)p; p += (size_t)4 * HH * FF * 2;
        unsigned short* WhhEb = (unsigned short*)p; p += (size_t)4 * HH * HH * 2;
        unsigned short* WihDb = (unsigned short*)p; p += (size_t)4 * HH * HH * 2;
        unsigned short* WhhDb = (unsigned short*)p; p += (size_t)4 * HH * HH * 2;
        size_t need = (size_t)(p - (char*)d_ws);

        if (ws_size >= need) {
            hipMemsetAsync(bar, 0, 4096, stream);
            k_cast_x<<<TT, 256, 0, stream>>>(x, xB);
            k_wcast<<<1024, 256, 0, stream>>>(Wih_e, WihEb, 4 * HH * FF / 4);
            k_wcast<<<1024, 256, 0, stream>>>(Whh_e, WhhEb, 4 * HH * HH / 4);
            k_wcast<<<1024, 256, 0, stream>>>(Wih_d, WihDb, 4 * HH * HH / 4);
            k_wcast<<<1024, 256, 0, stream>>>(Whh_d, WhhDb, 4 * HH * HH / 4);

            void* args[] = {
                (void*)&xB, (void*)&WihEb, (void*)&WhhEb, (void*)&b_e,
                (void*)&WihDb, (void*)&WhhDb, (void*)&b_d,
                (void*)&encB, (void*)&decR, (void*)&bar};
            hipLaunchCooperativeKernel((const void*)k_lstm_persist,
                                       dim3(NBLK), dim3(256), args, 0, stream);

            k_out_proj_r<<<dim3(TT, 4), 256, 0, stream>>>(decR, Wout, bout, out);
            return;
        }
    }

    // ================= fallback: round-4 verified path =================
    char* p = (char*)d_ws;
    unsigned short* encB  = (unsigned short*)p; p += (size_t)TT * SB * 2;
    unsigned short* dech0 = (unsigned short*)p; p += SB * 2;
    unsigned short* dech1 = (unsigned short*)p; p += SB * 2;
    float* cbuf = (float*)p; p += SB * 4;
    size_t used  = (size_t)(p - (char*)d_ws);
    size_t avail = ws_size > used ? ws_size - used : 0;

    const size_t WE_B = ((size_t)4 * HH * FF + (size_t)4 * HH * HH) * 2;
    const size_t WD_B = ((size_t)4 * HH * HH) * 2 * 2;
    const size_t CH8  = (size_t)8 * SB * 4;

    bool wbAll = (avail >= WE_B + WD_B + CH8);
    bool wbEnc = wbAll || (avail >= WE_B + CH8);

    unsigned short *WihEb = 0, *WhhEb = 0, *WihDb = 0, *WhhDb = 0;
    if (wbEnc) {
        WihEb = (unsigned short*)p; p += (size_t)4 * HH * FF * 2;
        WhhEb = (unsigned short*)p; p += (size_t)4 * HH * HH * 2;
        avail -= WE_B;
    }
    if (wbAll) {
        WihDb = (unsigned short*)p; p += (size_t)4 * HH * HH * 2;
        WhhDb = (unsigned short*)p; p += (size_t)4 * HH * HH * 2;
        avail -= WD_B;
    }
    int C = 8;
    if      (avail >= (size_t)64 * SB * 4) C = 64;
    else if (avail >= (size_t)32 * SB * 4) C = 32;
    else if (avail >= (size_t)16 * SB * 4) C = 16;
    float* chunk = (float*)p;

    hipMemsetAsync(cbuf, 0, SB * 4, stream);
    k_cast_x<<<TT, 256, 0, stream>>>(x, xB);
    if (wbEnc) {
        k_wcast<<<1024, 256, 0, stream>>>(Wih_e, WihEb, 4 * HH * FF / 4);
        k_wcast<<<1024, 256, 0, stream>>>(Whh_e, WhhEb, 4 * HH * HH / 4);
    }
    if (wbAll) {
        k_wcast<<<1024, 256, 0, stream>>>(Wih_d, WihDb, 4 * HH * HH / 4);
        k_wcast<<<1024, 256, 0, stream>>>(Whh_d, WhhDb, 4 * HH * HH / 4);
    }

    for (int t = 0; t < TT; ++t) {
        const unsigned short* A1 = xB + (size_t)t * BB * FF;
        const unsigned short* A2 = t ? encB + (size_t)(t - 1) * SB : (unsigned short*)0;
        unsigned short* hOut = encB + (size_t)t * SB;
        if (wbEnc) {
            if (t == 0)
                k_step_lds<1><<<256, 256, 0, stream>>>(A1, WihEb, FF, A2, WhhEb, HH,
                                                       1, b_e, cbuf, hOut, (float*)0);
            else
                k_step_lds<5><<<256, 256, 0, stream>>>(A1, WihEb, FF, A2, WhhEb, HH,
                                                       1, b_e, cbuf, hOut, (float*)0);
        } else {
            k_step_f32w<<<256, 256, 0, stream>>>(A1, Wih_e, FF, A2, Whh_e,
                                                 t ? HH : 0, b_e, cbuf, hOut, (float*)0);
        }
    }

    for (int t = 0; t < TT; ++t) {
        const unsigned short* A1 = encB + (size_t)t * SB;
        const unsigned short* A2 = (t == 0) ? encB + (size_t)(TT - 1) * SB
                                            : ((t & 1) ? dech1 : dech0);
        unsigned short* hOut = ((t + 1) & 1) ? dech1 : dech0;
        int l = t & (C - 1);
        float* ch = chunk + (size_t)l * SB;
        if (wbAll)
            k_step_lds<8><<<256, 256, 0, stream>>>(A1, WihDb, HH, A2, WhhDb, HH,
                                                   4, b_d, cbuf, hOut, ch);
        else
            k_step_f32w<<<256, 256, 0, stream>>>(A1, Wih_d, FF, A2, Whh_d, HH,
                                                 b_d, cbuf, hOut, ch);
        if (l == C - 1)
            k_out_proj<<<dim3(C, 4), 256, 0, stream>>>(chunk, Wout, bout, out,
                                                       t - (C - 1));
    }
}